// Round 9
// baseline (346.043 us; speedup 1.0000x reference)
//
#include <hip/hip_runtime.h>

#define NB 32
#define NL 512
#define NC 256

typedef __attribute__((ext_vector_type(8))) short short8v;   // 8 bf16
typedef __attribute__((ext_vector_type(4))) float f32x4;     // MFMA C/D

__device__ __forceinline__ unsigned short f2bf(float x) {
    unsigned int u = __float_as_uint(x);
    return (unsigned short)((u + 0x7FFFu + ((u >> 16) & 1u)) >> 16);  // RNE
}

// ---------------------------------------------------------------------------
// k_xct: xc = x + conv_e + conv_p -> bf16 tiled transpose xcT[b][lt][c][32]
// + rd[b,l] = sum_c xc*Wproj (wave shuffle reduce; x read exactly once).
// NOTE: rd therefore already contains the energy/pitch conv projections and
// the be+bp bias projections — k_ranges must add ONLY the Wd/bd terms.
// ---------------------------------------------------------------------------
__global__ __launch_bounds__(256) void k_xct(
    const float* __restrict__ x,
    const float* __restrict__ energ, const float* __restrict__ pitch,
    const float* __restrict__ We, const float* __restrict__ be,
    const float* __restrict__ Wp, const float* __restrict__ bp,
    const float* __restrict__ Wproj,
    unsigned short* __restrict__ xcT, float* __restrict__ rd)
{
    __shared__ float se[34], sp[34];
    __shared__ float part[4][32];
    int lt = blockIdx.x, b = blockIdx.y;
    int c = threadIdx.x;
    int lane = c & 63, wv = c >> 6;
    int l0 = lt * 32;
    if (c < 34) {
        int gl = l0 - 1 + c;
        bool ok = (gl >= 0) && (gl < NL);
        se[c] = ok ? energ[b*NL + gl] : 0.f;
        sp[c] = ok ? pitch[b*NL + gl] : 0.f;
    }
    __syncthreads();
    float we0 = We[c*3], we1 = We[c*3+1], we2 = We[c*3+2];
    float wp0 = Wp[c*3], wp1 = Wp[c*3+1], wp2 = Wp[c*3+2];
    float bb = be[c] + bp[c];
    float pw = Wproj[c];
    const float* xb = x + ((size_t)b*NL + l0)*NC + c;
    unsigned int w32[16];
#pragma unroll
    for (int l = 0; l < 32; ++l) {
        float conv = we0*se[l] + we1*se[l+1] + we2*se[l+2]
                   + wp0*sp[l] + wp1*sp[l+1] + wp2*sp[l+2] + bb;
        float v = xb[(size_t)l*NC] + conv;
        unsigned int bits = f2bf(v);
        if (l & 1) w32[l>>1] |= bits << 16;
        else       w32[l>>1]  = bits;
        float contrib = v * pw;
#pragma unroll
        for (int off = 32; off > 0; off >>= 1)
            contrib += __shfl_down(contrib, off, 64);
        if (lane == 0) part[wv][l] = contrib;
    }
    uint4* dst = (uint4*)(xcT + ((size_t)(b*16 + lt)*NC + c)*32);
    const uint4* src = (const uint4*)w32;
#pragma unroll
    for (int k = 0; k < 4; ++k) dst[k] = src[k];
    __syncthreads();
    if (c < 32)
        rd[b*NL + l0 + c] = part[0][c] + part[1][c] + part[2][c] + part[3][c];
}

// ---------------------------------------------------------------------------
// k_ranges: duration scan -> means; ranges = softplus(rd + Wd-conv projection
// + bd projection + bproj). ONLY the duration-conv terms here (rd has e/p).
// ---------------------------------------------------------------------------
__global__ __launch_bounds__(512) void k_ranges(
    const float* __restrict__ df, const int* __restrict__ di,
    const int* __restrict__ ilen,
    const float* __restrict__ Wd, const float* __restrict__ bd,
    const float* __restrict__ Wproj, const float* __restrict__ bproj,
    const float* __restrict__ rd,
    float* __restrict__ meanO, float* __restrict__ invrO, float* __restrict__ coefO)
{
    __shared__ float r2[4][8];
    __shared__ float pwS[4];
    __shared__ int sbuf[2][NL];
    int b = blockIdx.x;
    int l = threadIdx.x;
    int lane = l & 63, wv = l >> 6;

    float vals[4] = {0.f, 0.f, 0.f, 0.f};
    if (l < 256) {
        float w = Wproj[l];
        vals[0] = Wd[l*3]*w; vals[1] = Wd[l*3+1]*w; vals[2] = Wd[l*3+2]*w;
        vals[3] = bd[l]*w;
    }
#pragma unroll
    for (int q = 0; q < 4; ++q) {
        float v = vals[q];
#pragma unroll
        for (int off = 32; off > 0; off >>= 1) v += __shfl_down(v, off, 64);
        if (lane == 0) r2[q][wv] = v;
    }

    // inclusive scan of durations (ping-pong); first barrier also covers r2
    int d = di[b*NL + l];
    sbuf[0][l] = d;
    __syncthreads();
    if (l < 4) {
        float s = 0.f;
#pragma unroll
        for (int w8 = 0; w8 < 8; ++w8) s += r2[l][w8];
        pwS[l] = s;
    }
    int cur = 0;
    for (int off = 1; off < NL; off <<= 1) {
        int v = sbuf[cur][l];
        if (l >= off) v += sbuf[cur][l - off];
        sbuf[cur^1][l] = v;
        __syncthreads();
        cur ^= 1;
    }
    int incl = sbuf[cur][l];
    float mean = (float)incl - 0.5f*(float)d;

    int ro = b*NL + l;
    float fm1 = (l > 0)      ? df[ro-1] : 0.f;
    float f0  =                df[ro];
    float fp1 = (l < NL-1)   ? df[ro+1] : 0.f;
    float rin = rd[ro]
              + pwS[0]*fm1 + pwS[1]*f0 + pwS[2]*fp1
              + pwS[3] + bproj[0];
    float rng = (rin > 20.f) ? rin : log1pf(expf(rin));   // softplus
    bool pad = (l >= ilen[b]);
    float invr = 1.f / rng;
    meanO[ro] = mean;
    invrO[ro] = pad ? 1.f : invr;
    coefO[ro] = pad ? 0.f : 0.3989422804014327f * invr;   // 1/(r*sqrt(2pi))
}

// ---------------------------------------------------------------------------
// k_fused: per (b, 32-t tile), exp computed ONCE, all prob math in fp32:
//   A: fp32 p -> 64 registers + per-t partial sums -> in-block dv
//   B: w = p*dv (fp32): store fp32 w to outW; bf16(w) -> swizzled LDS (b128)
//      (bf16 ONLY on normalized w in [0,1] — raw p may be fp32-subnormal and
//       bf16-flushes; that was round-6's tail-zone bug)
//   C: MFMA out[t,c] = sum_l w*xc over flagged K-chunks (round-5 layout)
// ---------------------------------------------------------------------------
__global__ __launch_bounds__(256) void k_fused(
    const unsigned short* __restrict__ xcT,
    const float* __restrict__ meanA, const float* __restrict__ invrA,
    const float* __restrict__ coefA,
    float* __restrict__ outX, float* __restrict__ outW, int T)
{
    __shared__ __align__(16) unsigned short wT[32 * NL];  // 32 KB, swizzled
    __shared__ float red[8][32];
    __shared__ float dinvS[32];
    __shared__ unsigned int fl[16];

    int b = blockIdx.y;
    int t0 = blockIdx.x << 5;
    int tid = threadIdx.x;
    int tcol = tid & 31;
    int lbase = tid >> 5;
    if (tid < 16) fl[tid] = 0u;
    __syncthreads();

    int t = t0 + tcol;
    float fr = (float)t + 0.5f;
    const float* mB = meanA + b*NL;
    const float* iB = invrA + b*NL;
    const float* cB = coefA + b*NL;
    char* wbase = (char*)wT;
    int sw = (tcol & 7) << 4;

    // phase A: fp32 probs into registers + fused per-t partial sums
    float pv[8][8];
    float partial = 0.f;
#pragma unroll
    for (int i = 0; i < 8; ++i) {
        int ci = lbase + (i << 3);       // chunk 0..63 (8 l each)
        int lc = ci << 3;
        const float4 m0  = *(const float4*)(mB + lc);
        const float4 m1  = *(const float4*)(mB + lc + 4);
        const float4 iv0 = *(const float4*)(iB + lc);
        const float4 iv1 = *(const float4*)(iB + lc + 4);
        const float4 cv0 = *(const float4*)(cB + lc);
        const float4 cv1 = *(const float4*)(cB + lc + 4);
        float mm[8] = {m0.x,m0.y,m0.z,m0.w,m1.x,m1.y,m1.z,m1.w};
        float ii[8] = {iv0.x,iv0.y,iv0.z,iv0.w,iv1.x,iv1.y,iv1.z,iv1.w};
        float cc[8] = {cv0.x,cv0.y,cv0.z,cv0.w,cv1.x,cv1.y,cv1.z,cv1.w};
        float sum = 0.f;
#pragma unroll
        for (int j = 0; j < 8; ++j) {
            float z = (fr - mm[j]) * ii[j];
            float z2 = z*z;
            float p = (z2 < 450.f) ? cc[j]*__expf(-0.5f*z2) : 0.f;
            pv[i][j] = p;
            sum += p;
        }
        if (sum > 0.f) fl[ci >> 2] = 1u;           // benign same-value race
        partial += sum;
    }
    red[lbase][tcol] = partial;
    __syncthreads();
    if (tid < 32) {
        float s = 0.f;
#pragma unroll
        for (int g = 0; g < 8; ++g) s += red[g][tid];
        dinvS[tid] = 1.f / (s + 1e-20f);
    }
    __syncthreads();
    float dv = dinvS[tcol];

    // phase B: normalize in fp32; fp32 w -> outW; bf16(w) -> swizzled LDS
    bool tok = t < T;
    float* ow = outW + (size_t)b*NL*T + t;
#pragma unroll
    for (int i = 0; i < 8; ++i) {
        int ci = lbase + (i << 3);
        int lc = ci << 3;
        union { unsigned int u[4]; short8v v; } pk;
#pragma unroll
        for (int j = 0; j < 4; ++j) {
            float w0 = pv[i][2*j]   * dv;
            float w1 = pv[i][2*j+1] * dv;
            pk.u[j] = (unsigned int)f2bf(w0) | ((unsigned int)f2bf(w1) << 16);
            if (tok) {
                ow[(size_t)(lc + 2*j)   * T] = w0;
                ow[(size_t)(lc + 2*j+1) * T] = w1;
            }
        }
        *(short8v*)(wbase + (((tcol << 10) + (ci << 4)) ^ sw)) = pk.v;
    }
    __syncthreads();

    // phase C: MFMA over flagged K-chunks. wave wvid owns c in [wvid*64, +64).
    int lane = tid & 63;
    int wvid = tid >> 6;
    int g = lane >> 4;
    int m = lane & 15;
    f32x4 acc[2][4];
#pragma unroll
    for (int mt = 0; mt < 2; ++mt)
#pragma unroll
        for (int nt = 0; nt < 4; ++nt) acc[mt][nt] = (f32x4){0.f,0.f,0.f,0.f};

    const unsigned short* xb = xcT + (size_t)b * 16 * 8192;   // [lt][c][32]
    int asw = (m & 7) << 4;

    for (int ks = 0; ks < 16; ++ks) {
        if (fl[ks] == 0u) continue;
        const unsigned short* xk = xb + ks*8192 + g*8;
        short8v a0 = *(const short8v*)(wbase + (((m << 10)      + ks*64 + (g << 4)) ^ asw));
        short8v a1 = *(const short8v*)(wbase + ((((16+m) << 10) + ks*64 + (g << 4)) ^ asw));
#pragma unroll
        for (int nt = 0; nt < 4; ++nt) {
            short8v bf = *(const short8v*)(xk + (size_t)(wvid*64 + nt*16 + m)*32);
            acc[0][nt] = __builtin_amdgcn_mfma_f32_16x16x32_bf16(a0, bf, acc[0][nt], 0, 0, 0);
            acc[1][nt] = __builtin_amdgcn_mfma_f32_16x16x32_bf16(a1, bf, acc[1][nt], 0, 0, 0);
        }
    }

    // epilogue: D row(t)=g*4+r (+16*mt), col(c)=m (+16*nt +64*wvid)
    float* outB = outX + (size_t)b*T*NC + (size_t)(wvid*64 + m);
#pragma unroll
    for (int mt = 0; mt < 2; ++mt) {
#pragma unroll
        for (int r = 0; r < 4; ++r) {
            int tt = t0 + mt*16 + g*4 + r;
            if (tt < T) {
#pragma unroll
                for (int nt = 0; nt < 4; ++nt)
                    outB[(size_t)tt*NC + nt*16] = acc[mt][nt][r];
            }
        }
    }
}

// ---------------------------------------------------------------------------
extern "C" void kernel_launch(void* const* d_in, const int* in_sizes, int n_in,
                              void* d_out, int out_size, void* d_ws, size_t ws_size,
                              hipStream_t stream)
{
    const float* x   = (const float*)d_in[0];
    const float* df  = (const float*)d_in[1];
    const float* en  = (const float*)d_in[2];
    const float* pi  = (const float*)d_in[3];
    const float* Wd  = (const float*)d_in[4];
    const float* bd  = (const float*)d_in[5];
    const float* We  = (const float*)d_in[6];
    const float* be  = (const float*)d_in[7];
    const float* Wp  = (const float*)d_in[8];
    const float* bp  = (const float*)d_in[9];
    const float* Wpr = (const float*)d_in[10];
    const float* bpr = (const float*)d_in[11];
    const int*   di  = (const int*)d_in[12];
    const int*   il  = (const int*)d_in[13];

    int T = out_size / (NB * (NC + NL));   // out = B*T*C + B*L*T

    float* outX = (float*)d_out;
    float* outW = outX + (size_t)NB * T * NC;

    float* rdp   = (float*)d_ws;                       // B*L
    float* meanp = rdp   + NB*NL;
    float* invrp = meanp + NB*NL;
    float* coefp = invrp + NB*NL;
    unsigned short* xcT = (unsigned short*)(coefp + NB*NL);  // B*16*256*32 bf16

    hipLaunchKernelGGL(k_xct, dim3(16, NB), dim3(256), 0, stream,
                       x, en, pi, We, be, Wp, bp, Wpr, xcT, rdp);
    hipLaunchKernelGGL(k_ranges, dim3(NB), dim3(512), 0, stream,
                       df, di, il, Wd, bd, Wpr, bpr, rdp, meanp, invrp, coefp);
    hipLaunchKernelGGL(k_fused, dim3((T+31)/32, NB), dim3(256), 0, stream,
                       xcT, meanp, invrp, coefp, outX, outW, T);
}

// Round 11
// 330.194 us; speedup vs baseline: 1.0480x; 1.0480x over previous
//
#include <hip/hip_runtime.h>

#define NB 32
#define NL 512
#define NC 256

typedef __attribute__((ext_vector_type(8))) short short8v;   // 8 bf16
typedef __attribute__((ext_vector_type(4))) float f32x4;     // MFMA C/D

__device__ __forceinline__ unsigned short f2bf(float x) {
    unsigned int u = __float_as_uint(x);
    return (unsigned short)((u + 0x7FFFu + ((u >> 16) & 1u)) >> 16);  // RNE
}

// ---------------------------------------------------------------------------
// k_xct: xc = x + conv_e + conv_p -> bf16 tiled transpose xcT[b][lt][c][32]
// + rd[b,l] = sum_c xc*Wproj. rd carries e/p conv + be/bp bias projections.
// ---------------------------------------------------------------------------
__global__ __launch_bounds__(256) void k_xct(
    const float* __restrict__ x,
    const float* __restrict__ energ, const float* __restrict__ pitch,
    const float* __restrict__ We, const float* __restrict__ be,
    const float* __restrict__ Wp, const float* __restrict__ bp,
    const float* __restrict__ Wproj,
    unsigned short* __restrict__ xcT, float* __restrict__ rd)
{
    __shared__ float se[34], sp[34];
    __shared__ float part[4][32];
    int lt = blockIdx.x, b = blockIdx.y;
    int c = threadIdx.x;
    int lane = c & 63, wv = c >> 6;
    int l0 = lt * 32;
    if (c < 34) {
        int gl = l0 - 1 + c;
        bool ok = (gl >= 0) && (gl < NL);
        se[c] = ok ? energ[b*NL + gl] : 0.f;
        sp[c] = ok ? pitch[b*NL + gl] : 0.f;
    }
    __syncthreads();
    float we0 = We[c*3], we1 = We[c*3+1], we2 = We[c*3+2];
    float wp0 = Wp[c*3], wp1 = Wp[c*3+1], wp2 = Wp[c*3+2];
    float bb = be[c] + bp[c];
    float pw = Wproj[c];
    const float* xb = x + ((size_t)b*NL + l0)*NC + c;
    unsigned int w32[16];
#pragma unroll
    for (int l = 0; l < 32; ++l) {
        float conv = we0*se[l] + we1*se[l+1] + we2*se[l+2]
                   + wp0*sp[l] + wp1*sp[l+1] + wp2*sp[l+2] + bb;
        float v = xb[(size_t)l*NC] + conv;
        unsigned int bits = f2bf(v);
        if (l & 1) w32[l>>1] |= bits << 16;
        else       w32[l>>1]  = bits;
        float contrib = v * pw;
#pragma unroll
        for (int off = 32; off > 0; off >>= 1)
            contrib += __shfl_down(contrib, off, 64);
        if (lane == 0) part[wv][l] = contrib;
    }
    uint4* dst = (uint4*)(xcT + ((size_t)(b*16 + lt)*NC + c)*32);
    const uint4* src = (const uint4*)w32;
#pragma unroll
    for (int k = 0; k < 4; ++k) dst[k] = src[k];
    __syncthreads();
    if (c < 32)
        rd[b*NL + l0 + c] = part[0][c] + part[1][c] + part[2][c] + part[3][c];
}

// ---------------------------------------------------------------------------
// k_ranges: duration scan -> means; ranges = softplus(rd + Wd/bd projection);
// also rmaxA[b] = max over valid l of range (for window binary search).
// ---------------------------------------------------------------------------
__global__ __launch_bounds__(512) void k_ranges(
    const float* __restrict__ df, const int* __restrict__ di,
    const int* __restrict__ ilen,
    const float* __restrict__ Wd, const float* __restrict__ bd,
    const float* __restrict__ Wproj, const float* __restrict__ bproj,
    const float* __restrict__ rd,
    float* __restrict__ meanO, float* __restrict__ invrO, float* __restrict__ coefO,
    float* __restrict__ rmaxA)
{
    __shared__ float r2[4][8];
    __shared__ float pwS[4];
    __shared__ float rm[8];
    __shared__ int sbuf[2][NL];
    int b = blockIdx.x;
    int l = threadIdx.x;
    int lane = l & 63, wv = l >> 6;

    float vals[4] = {0.f, 0.f, 0.f, 0.f};
    if (l < 256) {
        float w = Wproj[l];
        vals[0] = Wd[l*3]*w; vals[1] = Wd[l*3+1]*w; vals[2] = Wd[l*3+2]*w;
        vals[3] = bd[l]*w;
    }
#pragma unroll
    for (int q = 0; q < 4; ++q) {
        float v = vals[q];
#pragma unroll
        for (int off = 32; off > 0; off >>= 1) v += __shfl_down(v, off, 64);
        if (lane == 0) r2[q][wv] = v;
    }

    int d = di[b*NL + l];
    sbuf[0][l] = d;
    __syncthreads();
    if (l < 4) {
        float s = 0.f;
#pragma unroll
        for (int w8 = 0; w8 < 8; ++w8) s += r2[l][w8];
        pwS[l] = s;
    }
    int cur = 0;
    for (int off = 1; off < NL; off <<= 1) {
        int v = sbuf[cur][l];
        if (l >= off) v += sbuf[cur][l - off];
        sbuf[cur^1][l] = v;
        __syncthreads();
        cur ^= 1;
    }
    int incl = sbuf[cur][l];
    float mean = (float)incl - 0.5f*(float)d;

    int ro = b*NL + l;
    float fm1 = (l > 0)      ? df[ro-1] : 0.f;
    float f0  =                df[ro];
    float fp1 = (l < NL-1)   ? df[ro+1] : 0.f;
    float rin = rd[ro]
              + pwS[0]*fm1 + pwS[1]*f0 + pwS[2]*fp1
              + pwS[3] + bproj[0];
    float rng = (rin > 20.f) ? rin : log1pf(expf(rin));   // softplus
    bool pad = (l >= ilen[b]);
    float invr = 1.f / rng;
    meanO[ro] = mean;
    invrO[ro] = pad ? 1.f : invr;
    coefO[ro] = pad ? 0.f : 0.3989422804014327f * invr;   // 1/(r*sqrt(2pi))

    // rmax over valid l
    float rv = pad ? 0.f : rng;
#pragma unroll
    for (int off = 32; off > 0; off >>= 1)
        rv = fmaxf(rv, __shfl_down(rv, off, 64));
    if (lane == 0) rm[wv] = rv;
    __syncthreads();
    if (l == 0) {
        float mx = rm[0];
#pragma unroll
        for (int w8 = 1; w8 < 8; ++w8) mx = fmaxf(mx, rm[w8]);
        rmaxA[b] = mx;
    }
}

// ---------------------------------------------------------------------------
// k_gemmx: per (b, 32-t tile). Window-restricted via monotone means:
//   binary-search l-range [lo,hi) s.t. outside p==0 (z^2 cutoff, rmax bound);
//   pass 1: restricted exps -> per-t denominator -> dinvA[b][t]
//   pass 2: recompute, w = p*dv, bf16 -> swizzled LDS (chunk-aligned coverage)
//   MFMA out[t,c] = sum_l w*xc over flagged chunks. NO outW here.
// ---------------------------------------------------------------------------
__global__ __launch_bounds__(256) void k_gemmx(
    const unsigned short* __restrict__ xcT,
    const float* __restrict__ meanA, const float* __restrict__ invrA,
    const float* __restrict__ coefA, const float* __restrict__ rmaxA,
    float* __restrict__ outX, float* __restrict__ dinvA, int T)
{
    __shared__ __align__(16) unsigned short wT[32 * NL];  // 32 KB, swizzled
    __shared__ float red[8][32];
    __shared__ float dinvS[32];
    __shared__ unsigned int fl[16];
    __shared__ int rngS[2];

    int b = blockIdx.y;
    int t0 = blockIdx.x << 5;
    int tid = threadIdx.x;
    int tcol = tid & 31;
    int lbase = tid >> 5;
    const float* mB = meanA + b*NL;
    const float* iB = invrA + b*NL;
    const float* cB = coefA + b*NL;
    if (tid < 16) fl[tid] = 0u;
    if (tid == 0) {
        float span = 21.25f * rmaxA[b] + 1.0f;
        float A = (float)t0 + 0.5f - span;
        float Bv = (float)(t0 + 31) + 0.5f + span;
        int lo = 0, hi = 0;
        for (int s = 256; s; s >>= 1) if (lo + s <= NL && mB[lo + s - 1] <  A ) lo += s;
        for (int s = 256; s; s >>= 1) if (hi + s <= NL && mB[hi + s - 1] <= Bv) hi += s;
        rngS[0] = (lo >> 5) << 2;            // chunk-aligned subchunk range
        rngS[1] = ((hi + 31) >> 5) << 2;
    }
    __syncthreads();
    int sc0 = rngS[0], sc1 = rngS[1];
    float fr = (float)(t0 + tcol) + 0.5f;
    char* wbase = (char*)wT;
    int sw = (tcol & 7) << 4;

    // pass 1: restricted exps, per-t partial sums, nonzero flags
    float partial = 0.f;
    for (int ci = sc0 + lbase; ci < sc1; ci += 8) {
        int lc = ci << 3;
        const float4 m0  = *(const float4*)(mB + lc);
        const float4 m1  = *(const float4*)(mB + lc + 4);
        const float4 iv0 = *(const float4*)(iB + lc);
        const float4 iv1 = *(const float4*)(iB + lc + 4);
        const float4 cv0 = *(const float4*)(cB + lc);
        const float4 cv1 = *(const float4*)(cB + lc + 4);
        float mm[8] = {m0.x,m0.y,m0.z,m0.w,m1.x,m1.y,m1.z,m1.w};
        float ii[8] = {iv0.x,iv0.y,iv0.z,iv0.w,iv1.x,iv1.y,iv1.z,iv1.w};
        float cc[8] = {cv0.x,cv0.y,cv0.z,cv0.w,cv1.x,cv1.y,cv1.z,cv1.w};
        float sum = 0.f;
#pragma unroll
        for (int j = 0; j < 8; ++j) {
            float z = (fr - mm[j]) * ii[j];
            float z2 = z*z;
            sum += (z2 < 450.f) ? cc[j]*__expf(-0.5f*z2) : 0.f;
        }
        if (sum > 0.f) fl[ci >> 2] = 1u;           // benign same-value race
        partial += sum;
    }
    red[lbase][tcol] = partial;
    __syncthreads();
    if (tid < 32) {
        float s = 0.f;
#pragma unroll
        for (int g = 0; g < 8; ++g) s += red[g][tid];
        float dvv = 1.f / (s + 1e-20f);
        dinvS[tid] = dvv;
        int t = t0 + tid;
        if (t < T) dinvA[(size_t)b*T + t] = dvv;
    }
    __syncthreads();
    float dv = dinvS[tcol];

    // pass 2: recompute restricted p, w = p*dv, bf16 -> swizzled LDS
    for (int ci = sc0 + lbase; ci < sc1; ci += 8) {
        int lc = ci << 3;
        const float4 m0  = *(const float4*)(mB + lc);
        const float4 m1  = *(const float4*)(mB + lc + 4);
        const float4 iv0 = *(const float4*)(iB + lc);
        const float4 iv1 = *(const float4*)(iB + lc + 4);
        const float4 cv0 = *(const float4*)(cB + lc);
        const float4 cv1 = *(const float4*)(cB + lc + 4);
        float mm[8] = {m0.x,m0.y,m0.z,m0.w,m1.x,m1.y,m1.z,m1.w};
        float ii[8] = {iv0.x,iv0.y,iv0.z,iv0.w,iv1.x,iv1.y,iv1.z,iv1.w};
        float cc[8] = {cv0.x,cv0.y,cv0.z,cv0.w,cv1.x,cv1.y,cv1.z,cv1.w};
        union { unsigned int u[4]; short8v v; } pk;
#pragma unroll
        for (int j = 0; j < 4; ++j) {
            float z0 = (fr - mm[2*j])   * ii[2*j];
            float z1 = (fr - mm[2*j+1]) * ii[2*j+1];
            float q0 = z0*z0, q1 = z1*z1;
            float w0 = (q0 < 450.f) ? cc[2*j]  *__expf(-0.5f*q0)*dv : 0.f;
            float w1 = (q1 < 450.f) ? cc[2*j+1]*__expf(-0.5f*q1)*dv : 0.f;
            pk.u[j] = (unsigned int)f2bf(w0) | ((unsigned int)f2bf(w1) << 16);
        }
        *(short8v*)(wbase + (((tcol << 10) + (ci << 4)) ^ sw)) = pk.v;
    }
    __syncthreads();

    // MFMA over flagged chunks. wave wvid owns c in [wvid*64, +64).
    int lane = tid & 63;
    int wvid = tid >> 6;
    int g = lane >> 4;
    int m = lane & 15;
    f32x4 acc[2][4];
#pragma unroll
    for (int mt = 0; mt < 2; ++mt)
#pragma unroll
        for (int nt = 0; nt < 4; ++nt) acc[mt][nt] = (f32x4){0.f,0.f,0.f,0.f};

    const unsigned short* xb = xcT + (size_t)b * 16 * 8192;   // [lt][c][32]
    int asw = (m & 7) << 4;

    for (int ks = 0; ks < 16; ++ks) {
        if (fl[ks] == 0u) continue;
        const unsigned short* xk = xb + ks*8192 + g*8;
        short8v a0 = *(const short8v*)(wbase + (((m << 10)      + ks*64 + (g << 4)) ^ asw));
        short8v a1 = *(const short8v*)(wbase + ((((16+m) << 10) + ks*64 + (g << 4)) ^ asw));
#pragma unroll
        for (int nt = 0; nt < 4; ++nt) {
            short8v bf = *(const short8v*)(xk + (size_t)(wvid*64 + nt*16 + m)*32);
            acc[0][nt] = __builtin_amdgcn_mfma_f32_16x16x32_bf16(a0, bf, acc[0][nt], 0, 0, 0);
            acc[1][nt] = __builtin_amdgcn_mfma_f32_16x16x32_bf16(a1, bf, acc[1][nt], 0, 0, 0);
        }
    }

    float* outB = outX + (size_t)b*T*NC + (size_t)(wvid*64 + m);
#pragma unroll
    for (int mt = 0; mt < 2; ++mt) {
#pragma unroll
        for (int r = 0; r < 4; ++r) {
            int tt = t0 + mt*16 + g*4 + r;
            if (tt < T) {
#pragma unroll
                for (int nt = 0; nt < 4; ++nt)
                    outB[(size_t)tt*NC + nt*16] = acc[mt][nt][r];
            }
        }
    }
}

// ---------------------------------------------------------------------------
// k_weightsC: outW[b,l,t] with t-CONTIGUOUS sweeps per l-row.
// Per l: window [wlo,whi) s.t. outside z^2>=450 => w==0 exactly; zero runs
// stream at full BW, values computed with the same cutoff + dinvA.
// ---------------------------------------------------------------------------
__global__ __launch_bounds__(256) void k_weightsC(
    const float* __restrict__ meanA, const float* __restrict__ invrA,
    const float* __restrict__ coefA, const float* __restrict__ dinvA,
    float* __restrict__ outW, int T)
{
    __shared__ float sm[32], si[32], sc[32];
    __shared__ int wlo[32], whi[32];
    int lt = blockIdx.x, b = blockIdx.y;
    int tid = threadIdx.x;
    int l0 = lt * 32;
    if (tid < 32) {
        float m  = meanA[b*NL + l0 + tid];
        float iv = invrA[b*NL + l0 + tid];
        float cf = coefA[b*NL + l0 + tid];
        sm[tid] = m; si[tid] = iv; sc[tid] = cf;
        float span = 21.25f / iv + 1.0f;          // 21.25*r + 1
        int a  = (int)floorf(m - span);
        int b2 = (int)ceilf(m + span) + 1;
        if (cf == 0.f) { a = 0; b2 = 0; }         // pad row: all zeros
        wlo[tid] = max(0, a);
        whi[tid] = min(T, b2);
    }
    __syncthreads();
    const float* dB = dinvA + (size_t)b*T;
    float* ow = outW + ((size_t)b*NL + l0)*T;
    int nch = (T + 1023) >> 10;
    for (int l = 0; l < 32; ++l) {
        float m = sm[l], iv = si[l], cf = sc[l];
        int lo = wlo[l], hi = whi[l];
        float* row = ow + (size_t)l*T;
        for (int ch = 0; ch < nch; ++ch) {
            int t4 = (ch << 10) + (tid << 2);
            if (t4 >= T) break;
            float v0 = 0.f, v1 = 0.f, v2 = 0.f, v3 = 0.f;
            if (t4 + 4 > lo && t4 < hi) {          // overlaps value window
                float f0v = (float)t4 + 0.5f;
                float z;
                z = (f0v        - m)*iv; v0 = (z*z < 450.f) ? cf*__expf(-0.5f*z*z)*dB[t4]   : 0.f;
                if (t4+1 < T) { z = (f0v+1.f - m)*iv; v1 = (z*z < 450.f) ? cf*__expf(-0.5f*z*z)*dB[t4+1] : 0.f; }
                if (t4+2 < T) { z = (f0v+2.f - m)*iv; v2 = (z*z < 450.f) ? cf*__expf(-0.5f*z*z)*dB[t4+2] : 0.f; }
                if (t4+3 < T) { z = (f0v+3.f - m)*iv; v3 = (z*z < 450.f) ? cf*__expf(-0.5f*z*z)*dB[t4+3] : 0.f; }
            }
            if (t4 + 4 <= T) {
                row[t4]   = v0; row[t4+1] = v1;
                row[t4+2] = v2; row[t4+3] = v3;
            } else {
                row[t4] = v0;
                if (t4+1 < T) row[t4+1] = v1;
                if (t4+2 < T) row[t4+2] = v2;
                if (t4+3 < T) row[t4+3] = v3;
            }
        }
    }
}

// ---------------------------------------------------------------------------
extern "C" void kernel_launch(void* const* d_in, const int* in_sizes, int n_in,
                              void* d_out, int out_size, void* d_ws, size_t ws_size,
                              hipStream_t stream)
{
    const float* x   = (const float*)d_in[0];
    const float* df  = (const float*)d_in[1];
    const float* en  = (const float*)d_in[2];
    const float* pi  = (const float*)d_in[3];
    const float* Wd  = (const float*)d_in[4];
    const float* bd  = (const float*)d_in[5];
    const float* We  = (const float*)d_in[6];
    const float* be  = (const float*)d_in[7];
    const float* Wp  = (const float*)d_in[8];
    const float* bp  = (const float*)d_in[9];
    const float* Wpr = (const float*)d_in[10];
    const float* bpr = (const float*)d_in[11];
    const int*   di  = (const int*)d_in[12];
    const int*   il  = (const int*)d_in[13];

    int T = out_size / (NB * (NC + NL));   // out = B*T*C + B*L*T

    float* outX = (float*)d_out;
    float* outW = outX + (size_t)NB * T * NC;

    unsigned short* xcT = (unsigned short*)d_ws;       // B*16*256*32 bf16 (16B-aligned)
    float* rdp   = (float*)(xcT + (size_t)NB*16*NC*32);
    float* meanp = rdp   + NB*NL;
    float* invrp = meanp + NB*NL;
    float* coefp = invrp + NB*NL;
    float* dinvp = coefp + NB*NL;                      // B*T
    float* rmaxp = dinvp + (size_t)NB*T;               // B

    hipLaunchKernelGGL(k_xct, dim3(16, NB), dim3(256), 0, stream,
                       x, en, pi, We, be, Wp, bp, Wpr, xcT, rdp);
    hipLaunchKernelGGL(k_ranges, dim3(NB), dim3(512), 0, stream,
                       df, di, il, Wd, bd, Wpr, bpr, rdp, meanp, invrp, coefp, rmaxp);
    hipLaunchKernelGGL(k_gemmx, dim3((T+31)/32, NB), dim3(256), 0, stream,
                       xcT, meanp, invrp, coefp, rmaxp, outX, dinvp, T);
    hipLaunchKernelGGL(k_weightsC, dim3(16, NB), dim3(256), 0, stream,
                       meanp, invrp, coefp, dinvp, outW, T);
}